// Round 15
// baseline (150.832 us; speedup 1.0000x reference)
//
#include <hip/hip_runtime.h>

#define D 256
#define CPS 4            // pass0 chunk-blocks per segment
#define TPB0 256
#define TPB1 1024        // phases kernel: 1 block/segment, 32 half-wave row-slots
#define SLOTS 32
#define PSTR (D + 1)

__device__ __forceinline__ unsigned bfbits(float f) {  // f32 -> bf16 bits, RNE
    unsigned u = __float_as_uint(f);
    return (u + 0x7fffu + ((u >> 16) & 1u)) >> 16;
}
__device__ __forceinline__ float bflo(unsigned u) { return __uint_as_float(u << 16); }
__device__ __forceinline__ float bfhi(unsigned u) { return __uint_as_float(u & 0xffff0000u); }

// ---------- kernel 1: pass 0 — mean partials + f32->bf16 conversion ----------
template<int USE_WS>
__global__ __launch_bounds__(TPB0, 8)
void pass0_k(const float* __restrict__ x, unsigned short* __restrict__ xb,
             const int* __restrict__ batch, float* __restrict__ part_out, int n)
{
    __shared__ float zp[8][D];
    __shared__ float sp[8];
    __shared__ int bnd[2];
    const int tid = threadIdx.x;
    const int s = blockIdx.x / CPS, k = blockIdx.x % CPS;
    const int hw = tid >> 5, l = tid & 31;

    if (tid < 2) {                       // lower_bound(batch, s+tid); L2-cached
        const int key = s + tid;
        int lo = 0, hi = n;
        while (lo < hi) { int mid = (lo + hi) >> 1; if (batch[mid] < key) lo = mid + 1; else hi = mid; }
        bnd[tid] = lo;
    }
    __syncthreads();
    const int start = bnd[0];
    const int cnt   = bnd[1] - start;
    const int csz   = (cnt + CPS - 1) / CPS;
    const int rbeg  = k * csz;
    const int rend  = min(cnt, rbeg + csz);

    float za[8] = {0,0,0,0,0,0,0,0};
    float s_acc = 0.f;
#pragma unroll 2
    for (int r = rbeg + hw; r < rend; r += 8) {
        const size_t boff = (size_t)(start + r) * D + l * 8;
        const float4 v0 = *(const float4*)(x + boff);
        const float4 v1 = *(const float4*)(x + boff + 4);
        if (USE_WS) {
            uint4 p;
            p.x = bfbits(v0.x) | (bfbits(v0.y) << 16);
            p.y = bfbits(v0.z) | (bfbits(v0.w) << 16);
            p.z = bfbits(v1.x) | (bfbits(v1.y) << 16);
            p.w = bfbits(v1.z) | (bfbits(v1.w) << 16);
            *(uint4*)(xb + boff) = p;
        }
        s_acc += 1.f;
        za[0] += v0.x; za[1] += v0.y; za[2] += v0.z; za[3] += v0.w;
        za[4] += v1.x; za[5] += v1.y; za[6] += v1.z; za[7] += v1.w;
    }
#pragma unroll
    for (int j = 0; j < 8; ++j) zp[hw][l * 8 + j] = za[j];
    if (l == 0) sp[hw] = s_acc;
    __syncthreads();
    float acc = 0.f;
#pragma unroll
    for (int h = 0; h < 8; ++h) acc += zp[h][tid];
    float* po = part_out + (size_t)(s * CPS + k) * PSTR;
    po[tid] = acc;
    if (tid == 0) {
        float st = 0.f;
#pragma unroll
        for (int h = 0; h < 8; ++h) st += sp[h];
        po[D] = st;
    }
}

// ---------- kernel 2: phases 1-3 + output, one 1024-thread block per segment ----
// w = exp(<x_i,S>) shift-free (|alpha| bounded ~40 << f32 overflow; eps form
// identical to reference). Weighted loop: 2 rows per slot-iteration (paired
// independent chains) to double memory-level parallelism over the serial
// dot->shfl->exp chain.
template<int USE_WS>
__global__ __launch_bounds__(TPB1, 8)
void phases_k(const float* __restrict__ x, const unsigned short* __restrict__ xb,
              const int* __restrict__ batch,
              const float* __restrict__ part, float* __restrict__ out, int n)
{
    __shared__ float zp[SLOTS][D];   // 32 KB
    __shared__ float sp[SLOTS];
    __shared__ float zs[D];
    __shared__ float red_e[16];
    __shared__ float red[2];
    __shared__ int bnd[2];
    const int tid  = threadIdx.x;
    const int s    = blockIdx.x;
    const int slot = tid >> 5;    // 0..31 row-slots (half-waves)
    const int l    = tid & 31;    // col group: cols l*8..l*8+7
    const int wv   = tid >> 6;    // 0..15

    if (tid < 2) {
        const int key = s + tid;
        int lo = 0, hi = n;
        while (lo < hi) { int mid = (lo + hi) >> 1; if (batch[mid] < key) lo = mid + 1; else hi = mid; }
        bnd[tid] = lo;
    }
    __syncthreads();
    const int start = bnd[0];
    const int cnt   = bnd[1] - start;

    // fold pass0 partials -> z0
    const float* pb = part + (size_t)s * CPS * PSTR;
    float z = 0.f;
    if (tid < D) {
#pragma unroll
        for (int kk = 0; kk < CPS; ++kk) z += pb[kk * PSTR + tid];
    }
    if (tid == 0) {
        float st = 0.f;
#pragma unroll
        for (int kk = 0; kk < CPS; ++kk) st += pb[kk * PSTR + D];
        red[0] = 1.f / (st + 1e-16f);
    }
    __syncthreads();
    z *= red[0];

    float Scol = 0.f;   // running S for column tid (tid < D)
    float zr[8];

    for (int ph = 1; ph <= 3; ++ph) {
        // ---- energy + squash; S += squash(z) ----
        float e = (tid < D) ? z * z : 0.f;
#pragma unroll
        for (int o = 32; o; o >>= 1) e += __shfl_xor(e, o);
        if ((tid & 63) == 0) red_e[wv] = e;
        __syncthreads();
        if (tid == 0) {
            float E = 0.f;
#pragma unroll
            for (int h = 0; h < 16; ++h) E += red_e[h];
            red[1] = (E > 0.f) ? (sqrtf(E) / (1.f + E)) : 0.f;
        }
        __syncthreads();
        if (tid < D) { Scol += z * red[1]; zs[tid] = Scol; }
        __syncthreads();
#pragma unroll
        for (int j = 0; j < 8; ++j) zr[j] = zs[l * 8 + j];

        // ---- weighted stream: 2 rows per slot-iteration, next pair prefetched ----
        float za[8] = {0,0,0,0,0,0,0,0};
        float s_acc = 0.f;
        int r = slot;
        bool vA = r < cnt, vB = (r + SLOTS) < cnt;
        uint4 uA = make_uint4(0,0,0,0), uB = uA;
        float4 fA0 = {0,0,0,0}, fA1 = fA0, fB0 = fA0, fB1 = fA0;
        if (vA) { const size_t o = (size_t)(start + r) * D + l * 8;
            if (USE_WS) uA = *(const uint4*)(xb + o);
            else { fA0 = *(const float4*)(x + o); fA1 = *(const float4*)(x + o + 4); } }
        if (vB) { const size_t o = (size_t)(start + r + SLOTS) * D + l * 8;
            if (USE_WS) uB = *(const uint4*)(xb + o);
            else { fB0 = *(const float4*)(x + o); fB1 = *(const float4*)(x + o + 4); } }

        while (vA) {
            const int rn = r + 2 * SLOTS;
            const bool wA = rn < cnt, wB = (rn + SLOTS) < cnt;
            uint4 nA = make_uint4(0,0,0,0), nB = nA;
            float4 gA0 = {0,0,0,0}, gA1 = gA0, gB0 = gA0, gB1 = gA0;
            if (wA) { const size_t o = (size_t)(start + rn) * D + l * 8;
                if (USE_WS) nA = *(const uint4*)(xb + o);
                else { gA0 = *(const float4*)(x + o); gA1 = *(const float4*)(x + o + 4); } }
            if (wB) { const size_t o = (size_t)(start + rn + SLOTS) * D + l * 8;
                if (USE_WS) nB = *(const uint4*)(xb + o);
                else { gB0 = *(const float4*)(x + o); gB1 = *(const float4*)(x + o + 4); } }

            float xa[8], xbv[8];
            if (USE_WS) {
                xa[0]=bflo(uA.x); xa[1]=bfhi(uA.x); xa[2]=bflo(uA.y); xa[3]=bfhi(uA.y);
                xa[4]=bflo(uA.z); xa[5]=bfhi(uA.z); xa[6]=bflo(uA.w); xa[7]=bfhi(uA.w);
                xbv[0]=bflo(uB.x); xbv[1]=bfhi(uB.x); xbv[2]=bflo(uB.y); xbv[3]=bfhi(uB.y);
                xbv[4]=bflo(uB.z); xbv[5]=bfhi(uB.z); xbv[6]=bflo(uB.w); xbv[7]=bfhi(uB.w);
            } else {
                xa[0]=fA0.x; xa[1]=fA0.y; xa[2]=fA0.z; xa[3]=fA0.w;
                xa[4]=fA1.x; xa[5]=fA1.y; xa[6]=fA1.z; xa[7]=fA1.w;
                xbv[0]=fB0.x; xbv[1]=fB0.y; xbv[2]=fB0.z; xbv[3]=fB0.w;
                xbv[4]=fB1.x; xbv[5]=fB1.y; xbv[6]=fB1.z; xbv[7]=fB1.w;
            }
            float dtA = 0.f, dtB = 0.f;
#pragma unroll
            for (int j = 0; j < 8; ++j) { dtA += xa[j] * zr[j]; dtB += xbv[j] * zr[j]; }
#pragma unroll
            for (int o = 16; o; o >>= 1) {            // interleaved chains
                dtA += __shfl_xor(dtA, o);
                dtB += __shfl_xor(dtB, o);
            }
            const float wgtA = __expf(dtA);
            const float wgtB = vB ? __expf(dtB) : 0.f;
            s_acc += wgtA + wgtB;
#pragma unroll
            for (int j = 0; j < 8; ++j) za[j] += wgtA * xa[j] + wgtB * xbv[j];

            uA = nA; uB = nB; fA0 = gA0; fA1 = gA1; fB0 = gB0; fB1 = gB1;
            vA = wA; vB = wB; r = rn;
        }

        // ---- in-block fold: 32 slots -> z ----
#pragma unroll
        for (int j = 0; j < 8; ++j) zp[slot][l * 8 + j] = za[j];
        if (l == 0) sp[slot] = s_acc;
        __syncthreads();
        z = 0.f;
        if (tid < D) {
#pragma unroll
            for (int h = 0; h < SLOTS; ++h) z += zp[h][tid];
        }
        if (tid == 0) {
            float st = 0.f;
#pragma unroll
            for (int h = 0; h < SLOTS; ++h) st += sp[h];
            red[0] = 1.f / (st + 1e-16f);
        }
        __syncthreads();
        z *= red[0];
    }

    if (tid < D) out[(size_t)s * D + tid] = z;
}

extern "C" void kernel_launch(void* const* d_in, const int* in_sizes, int n_in,
                              void* d_out, int out_size, void* d_ws, size_t ws_size,
                              hipStream_t stream) {
    const float* x   = (const float*)d_in[0];
    const int* batch = (const int*)d_in[1];
    float* out       = (float*)d_out;
    const int n = in_sizes[1];          // 262144
    const int B = out_size / D;         // 512

    const size_t xb_bytes = (size_t)n * D * sizeof(unsigned short);      // 134 MB
    const size_t pe = (size_t)B * CPS * PSTR;                            // partials
    const bool use_ws = ws_size >= xb_bytes + pe * sizeof(float);

    unsigned short* xb = (unsigned short*)d_ws;
    float* pA = use_ws ? (float*)((char*)d_ws + xb_bytes) : (float*)d_ws;

    if (use_ws) {
        pass0_k<1><<<B * CPS, TPB0, 0, stream>>>(x, xb, batch, pA, n);
        phases_k<1><<<B, TPB1, 0, stream>>>(x, xb, batch, pA, out, n);
    } else {
        pass0_k<0><<<B * CPS, TPB0, 0, stream>>>(x, xb, batch, pA, n);
        phases_k<0><<<B, TPB1, 0, stream>>>(x, xb, batch, pA, out, n);
    }
}